// Round 10
// baseline (208.874 us; speedup 1.0000x reference)
//
#include <hip/hip_runtime.h>
#include <math.h>

#define B_ 2
#define S_ 2048
#define E_ 768
#define H_ 12
#define D_ 64
#define M_ (B_*S_)   // 4096 rows total

typedef unsigned short ush;
using short8 = __attribute__((ext_vector_type(8))) short;   // 8 bf16 (4 VGPRs)
using f32x4  = __attribute__((ext_vector_type(4))) float;   // MFMA C/D

__device__ __forceinline__ ush f2b(float x) {               // fp32 -> bf16 RNE
    union { float f; unsigned u; } v; v.f = x;
    unsigned r = v.u + 0x7fffu + ((v.u >> 16) & 1u);
    return (ush)(r >> 16);
}
// fp32 pair -> packed bf16: round-half-up + v_perm_b32 (3 VALU ops).
__device__ __forceinline__ unsigned pack2(float x, float y) {
    unsigned bx = __float_as_uint(x) + 0x8000u;
    unsigned by = __float_as_uint(y) + 0x8000u;
    return __builtin_amdgcn_perm(by, bx, 0x07060302u);  // [bx.hi16 | by.hi16<<16]
}
// fp32 pair -> packed bf16 TRUNCATED (matches old Ps path): 1 v_perm op.
__device__ __forceinline__ unsigned pack2t(float x, float y) {
    return __builtin_amdgcn_perm(__float_as_uint(y), __float_as_uint(x), 0x07060302u);
}

// async global->LDS, 16B/lane. LDS dest = wave-uniform base + lane*16 (linear).
// Swizzled LDS content via permuted per-lane GLOBAL source (rule 21; XOR is
// an involution): physical chunk (lane&7) of row r holds logical chunk
// (lane&7)^(r&7); reads XOR the chunk index with (r&7).
#define GLOAD16(gp, lp) __builtin_amdgcn_global_load_lds( \
    (const __attribute__((address_space(1))) void*)(gp),   \
    (__attribute__((address_space(3))) void*)(lp), 16, 0, 0)

// ---------------------------------------------------------------------------
// Kernel 0: one-time fp32->bf16 convert + RoPE table. UNCHANGED.
// ---------------------------------------------------------------------------
__global__ __launch_bounds__(256) void convert_kernel(
    const float* __restrict__ q, const float* __restrict__ k, const float* __restrict__ v,
    const float* __restrict__ wq, const float* __restrict__ wk,
    const float* __restrict__ wv, const float* __restrict__ fw,
    ush* __restrict__ Xq, ush* __restrict__ Xk, ush* __restrict__ Xv,
    ush* __restrict__ Wqb, ush* __restrict__ Wkb, ush* __restrict__ Wvb,
    ush* __restrict__ Wfb, float2* __restrict__ rope)
{
    const int bid = blockIdx.x;
    const int t   = threadIdx.x;
    if (bid < 4608) {                         // 3 inputs, 1536 blocks each
        const int tz = bid / 1536, off = bid % 1536;
        const float* __restrict__ src = (tz == 0) ? q : (tz == 1) ? k : v;
        ush* __restrict__ dst = (tz == 0) ? Xq : (tz == 1) ? Xk : Xv;
        const size_t base = ((size_t)off * 256 + t) * 8;
        const float4 a = *(const float4*)&src[base];
        const float4 b = *(const float4*)&src[base + 4];
        uint4 o;
        o.x = pack2(a.x, a.y); o.y = pack2(a.z, a.w);
        o.z = pack2(b.x, b.y); o.w = pack2(b.z, b.w);
        *(uint4*)&dst[base] = o;
    } else if (bid < 5760) {                  // 4 weights, 288 blocks each
        const int id = bid - 4608;
        const int tz = id / 288, off = id % 288;
        const float* __restrict__ src = (tz == 0) ? wq : (tz == 1) ? wk : (tz == 2) ? wv : fw;
        ush* __restrict__ dst = (tz == 0) ? Wqb : (tz == 1) ? Wkb : (tz == 2) ? Wvb : Wfb;
        const size_t base = ((size_t)off * 256 + t) * 8;
        const float4 a = *(const float4*)&src[base];
        const float4 b = *(const float4*)&src[base + 4];
        uint4 o;
        o.x = pack2(a.x, a.y); o.y = pack2(a.z, a.w);
        o.z = pack2(b.x, b.y); o.w = pack2(b.z, b.w);
        *(uint4*)&dst[base] = o;
    } else {                                  // rope table: 65536 entries
        const int idx = (bid - 5760) * 256 + t;
        const int s = idx >> 5, dp = idx & 31;
        const float invf = expf(-(float)dp * (9.210340371976184f / 32.f)); // 10000^(-dp/32)
        float sn, cs;
        sincosf((float)s * invf, &sn, &cs);
        rope[idx] = make_float2(cs, sn);
    }
}

// ---------------------------------------------------------------------------
// Kernel 1: FUSED QKV projection. UNCHANGED.
// ---------------------------------------------------------------------------
__global__ __launch_bounds__(256, 4) void qkv_mfma_kernel(
    const ush* __restrict__ Xq, const ush* __restrict__ Xk, const ush* __restrict__ Xv,
    const ush* __restrict__ Wall,
    const float* __restrict__ bq, const float* __restrict__ bk, const float* __restrict__ bv,
    const float2* __restrict__ rope,
    ush* __restrict__ Qb, ush* __restrict__ Kb, ush* __restrict__ Vtb)
{
    __shared__ ush As[128 * 64];   // [m][k], chunk-swizzled, 16 KB
    __shared__ ush Bs[128 * 64];   // [n][k], chunk-swizzled, 16 KB

    // bijective XCD swizzle: 576 blocks = 8 XCDs x 72 contiguous
    const int bid0 = blockIdx.x + 32 * blockIdx.y;
    const int bid  = (bid0 & 7) * 72 + (bid0 >> 3);
    const int bx   = bid & 31;                 // m-block 0..31
    const int by   = bid >> 5;                 // n-block 0..17

    const int z   = by / 6;                    // 0=Q 1=K 2=V
    const int byz = by - z * 6;                // n-block within z
    const int n0  = by * 128;                  // row in Wall
    const ush* __restrict__ X = (z == 0) ? Xq : (z == 1) ? Xk : Xv;
    const float* __restrict__ bias = (z == 0) ? bq : (z == 1) ? bk : bv;

    const int m0 = bx * 128;
    const int t  = threadIdx.x;
    const int wid  = t >> 6;
    const int lane = t & 63;
    const int quad = lane >> 4;
    const int l16  = lane & 15;
    const int wr  = (wid >> 1) * 64;           // wave row offset (0/64)
    const int wcn = (wid & 1) * 64;            // wave col offset (0/64)
    const int h   = byz * 2 + (wid & 1);       // this wave's head (0..11)
    const int srow = lane >> 3;                // staging row within 8-row group
    const int schk = lane & 7;                 // staging physical 16B chunk

    f32x4 acc[4][4];
    #pragma unroll
    for (int i = 0; i < 4; ++i)
        #pragma unroll
        for (int j = 0; j < 4; ++j) acc[i][j] = (f32x4){0.f, 0.f, 0.f, 0.f};

    for (int kt = 0; kt < E_ / 64; ++kt) {
        const int kb = kt * 64;
        // stage: each wave 32 A-rows + 32 B-rows (8 gload/thread)
        #pragma unroll
        for (int j = 0; j < 4; ++j) {
            const int r = wid * 32 + j * 8 + srow;
            const int c = schk ^ (r & 7);
            GLOAD16(&X[(size_t)(m0 + r) * E_ + kb + c * 8], &As[(wid * 32 + j * 8) * 64]);
            GLOAD16(&Wall[(size_t)(n0 + r) * E_ + kb + c * 8], &Bs[(wid * 32 + j * 8) * 64]);
        }
        __syncthreads();   // vmcnt drained -> tile visible (TLP across blocks hides)

        #pragma unroll
        for (int ks = 0; ks < 2; ++ks) {
            short8 bfr[4];
            #pragma unroll
            for (int nj = 0; nj < 4; ++nj) {
                const int rn = wcn + nj * 16 + l16;
                bfr[nj] = *(const short8*)&Bs[rn * 64 + ((quad + ks * 4) ^ (rn & 7)) * 8];
            }
            #pragma unroll
            for (int mi = 0; mi < 4; ++mi) {
                const int rm = wr + mi * 16 + l16;
                short8 a = *(const short8*)&As[rm * 64 + ((quad + ks * 4) ^ (rm & 7)) * 8];
                #pragma unroll
                for (int nj = 0; nj < 4; ++nj)
                    acc[mi][nj] = __builtin_amdgcn_mfma_f32_16x16x32_bf16(a, bfr[nj], acc[mi][nj], 0, 0, 0);
            }
        }
        __syncthreads();   // all reads done before next tile overwrite
    }

    // ---- epilogue (per-wave head h; cols d = nj*16+l16 in [0,64)) ----
    if (z < 2) {
        ush* __restrict__ Ob = (z == 0) ? Qb : Kb;
        const bool even = (l16 & 1) == 0;
        #pragma unroll
        for (int nj = 0; nj < 4; ++nj) {
            const int d = nj * 16 + l16;
            const float bw = bias[h * 64 + d];
            #pragma unroll
            for (int mi = 0; mi < 4; ++mi) {
                #pragma unroll
                for (int r = 0; r < 4; ++r) {
                    const int m = m0 + wr + mi * 16 + quad * 4 + r;
                    const int bb = m >> 11, s = m & (S_ - 1);
                    const float v = acc[mi][nj][r] + bw;
                    const float vp = __shfl_xor(v, 1);           // partner (d^1)
                    if (even) {                                  // even lane stores the pair
                        const float2 cs2 = rope[s * 32 + (d >> 1)];
                        const float re = v  * cs2.x - vp * cs2.y;
                        const float ro = vp * cs2.x + v  * cs2.y;
                        const size_t o = (((size_t)bb * H_ + h) * S_ + s) * (size_t)D_ + d;
                        *(unsigned*)&Ob[o] = pack2(re, ro);
                    }
                }
            }
        }
    } else {
        // V: per-wave 64x64 LDS transpose (chunk-XOR swizzled, pitch 64),
        // then 128B-contiguous uint4 stores of V^T rows. Wave-private region:
        // waves 0,1 use As halves; waves 2,3 use Bs halves (both dead now).
        ush* Tb = (wid < 2) ? &As[wid * 4096] : &Bs[(wid - 2) * 4096];
        #pragma unroll
        for (int nj = 0; nj < 4; ++nj) {
            const int d = nj * 16 + l16;
            const float bw = bias[h * 64 + d];
            const int g = (d & 7) << 3;
            #pragma unroll
            for (int mi = 0; mi < 4; ++mi) {
                const int s_l = mi * 16 + quad * 4;
                const int sx  = s_l ^ g;       // XOR touches bits>=3 only; pair stays aligned
                *(unsigned*)&Tb[d * 64 + sx]     = pack2(acc[mi][nj][0] + bw, acc[mi][nj][1] + bw);
                *(unsigned*)&Tb[d * 64 + sx + 2] = pack2(acc[mi][nj][2] + bw, acc[mi][nj][3] + bw);
            }
        }
        __syncthreads();
        const int bb = (m0 + wr) >> 11;
        const int sb = (m0 + wr) & (S_ - 1);
        #pragma unroll
        for (int i = 0; i < 8; ++i) {
            const int d2 = (lane >> 3) + i * 8;
            const int c2 = lane & 7;
            const uint4 val = *(const uint4*)&Tb[d2 * 64 + ((c2 ^ (d2 & 7)) * 8)];
            const size_t o = (((size_t)bb * H_ + h) * D_ + d2) * (size_t)S_ + sb + c2 * 8;
            *(uint4*)&Vtb[o] = val;
        }
    }
}

// ---------------------------------------------------------------------------
// Kernel 2: MFMA flash attention. R9 changes (ONLY kernel changed):
// SWAPPED QK^T (Sc = mfma(aK, aQ)) makes each lane hold a full P-column
// slice for ITS OWN q (q = l16): softmax is fully in-register (hp = 1
// scalar/lane; kbv = broadcast float4 from kb_all), P->bf16 via 1-op
// truncating v_perm (bit-identical to old Ps truncation), and the PV
// A-frag is rebuilt with 16 __shfl + 8 selects instead of the Ps LDS
// round-trip (16 ds_write_b16 + 2 ds_read_b128 + lgkm chain).
// Ps (9216 B) deleted -> LDS 40960 B -> EXACTLY 4 blocks/CU (was 3).
// launch_bounds(256,4) caps VGPR<=128 so registers don't cap the 4th block.
// Shuffle index algebra: dest lane (quad,l16), A-frag word w of half h is
// q{01,23}[2h + (quad>>1)] pulled from lane ((quad&1)*2 + (w>>1))*16 + l16.
// ---------------------------------------------------------------------------
__global__ __launch_bounds__(256, 4) void attn_kernel(
    const ush* __restrict__ Qb, const ush* __restrict__ Kb, const ush* __restrict__ Vtb,
    const float* __restrict__ pb, const int* __restrict__ mask, const float* __restrict__ coeff,
    ush* __restrict__ Att)
{
    __shared__ ush  Ks[2][64 * 64];    // ping-pong [key][d], chunk-swizzled, 16 KB
    __shared__ ush  Vs[2][64 * 64];    // ping-pong [d][key], chunk-swizzled, 16 KB
    __shared__ float kb_all[S_];       // per-key bias (pre-scaled by log2e), 8 KB

    const int q0 = blockIdx.x * 64;
    const int h  = blockIdx.y;
    const int b  = blockIdx.z;
    const int t  = threadIdx.x;
    const int wid = t >> 6;
    const int lane = t & 63;
    const int quad = lane >> 4;
    const int l16  = lane & 15;
    const int srow = lane >> 3;
    const int schk = lane & 7;

    const int bh = b * H_ + h;
    const float ch = coeff[h];
    const float LOG2E = 1.44269504f;

    // per-key bias for the whole row: ((mask?0:-1e30) - ch*pb[k]) * log2e
    #pragma unroll
    for (int i = 0; i < 8; ++i) {
        const int idx = t + i * 256;
        const int gi = b * S_ + idx;
        kb_all[idx] = ((mask[gi] ? 0.f : -1e30f) - ch * pb[gi]) * LOG2E;
    }

    // register ones B-frag: output col 0 = 1.0, rest 0 (row-sum column)
    short8 b1v;
    {
        const short v1 = (l16 == 0) ? (short)0x3F80 : (short)0;
        b1v = (short8){v1, v1, v1, v1, v1, v1, v1, v1};
    }

    const int qrow = q0 + wid * 16 + l16;
    short8 aQ[2];
    #pragma unroll
    for (int ks = 0; ks < 2; ++ks)
        aQ[ks] = *(const short8*)&Qb[((size_t)bh * S_ + qrow) * D_ + quad * 8 + ks * 32];

    // swapped layout: this lane's q is qrow (= l16 within wave tile)
    const float hp_l = ch * pb[b * S_ + qrow] * LOG2E;

    f32x4 O[5];                        // O[4] = row-sum accumulator (ones frag)
    #pragma unroll
    for (int g = 0; g < 5; ++g) O[g] = (f32x4){0.f, 0.f, 0.f, 0.f};

    // prologue: stage tile 0 into buffer 0
    #pragma unroll
    for (int j = 0; j < 2; ++j) {
        const int r8 = wid * 16 + j * 8;
        const int r  = r8 + srow;
        const int c  = schk ^ (r & 7);
        GLOAD16(&Kb[((size_t)bh * S_ + r) * D_ + c * 8], &Ks[0][r8 * 64]);
        GLOAD16(&Vtb[((size_t)bh * D_ + r) * S_ + c * 8], &Vs[0][r8 * 64]);
    }
    __syncthreads();   // drains vmcnt; also orders kb_all init

    const int srcA = ((quad & 1) * 2) * 16 + l16;   // shuffle sources (words 0,1)
    const int srcB = srcA + 16;                     // (words 2,3)
    const bool loq = (quad < 2);                    // dest cg select: quads 0,1 vs 2,3

    int p = 0;
    for (int kt = 0; kt < S_ / 64; ++kt) {
        // issue next tile's loads (latency hides under QK/softmax/PV)
        if (kt + 1 < S_ / 64) {
            const int kn = (kt + 1) * 64;
            #pragma unroll
            for (int j = 0; j < 2; ++j) {
                const int r8 = wid * 16 + j * 8;
                const int r  = r8 + srow;
                const int c  = schk ^ (r & 7);
                GLOAD16(&Kb[((size_t)bh * S_ + kn + r) * D_ + c * 8], &Ks[p ^ 1][r8 * 64]);
                GLOAD16(&Vtb[((size_t)bh * D_ + r) * S_ + kn + c * 8], &Vs[p ^ 1][r8 * 64]);
            }
        }

        // ---- QK^T, SWAPPED: Sc[cg][r] = S[q = qrow][k = kt*64 + cg*16 + quad*4 + r]
        f32x4 Sc[4];
        #pragma unroll
        for (int cg = 0; cg < 4; ++cg) Sc[cg] = (f32x4){0.f, 0.f, 0.f, 0.f};
        __builtin_amdgcn_s_setprio(1);
        #pragma unroll
        for (int ks = 0; ks < 2; ++ks) {
            #pragma unroll
            for (int cg = 0; cg < 4; ++cg) {
                const int rk = cg * 16 + l16;
                short8 aK = *(const short8*)&Ks[p][rk * 64 + ((quad + ks * 4) ^ (rk & 7)) * 8];
                Sc[cg] = __builtin_amdgcn_mfma_f32_16x16x32_bf16(aK, aQ[ks], Sc[cg], 0, 0, 0);
            }
        }
        __builtin_amdgcn_s_setprio(0);

        // ---- in-register softmax numerators (bf16-truncated, as before) ----
        unsigned q01[4], q23[4];   // packed pairs: (r0,r1) and (r2,r3) per cg
        #pragma unroll
        for (int cg = 0; cg < 4; ++cg) {
            const float4 kv = *(const float4*)&kb_all[kt * 64 + cg * 16 + quad * 4];
            const float pe0 = __builtin_amdgcn_exp2f(fmaf(Sc[cg][0], 0.18033688f, hp_l + kv.x));
            const float pe1 = __builtin_amdgcn_exp2f(fmaf(Sc[cg][1], 0.18033688f, hp_l + kv.y));
            const float pe2 = __builtin_amdgcn_exp2f(fmaf(Sc[cg][2], 0.18033688f, hp_l + kv.z));
            const float pe3 = __builtin_amdgcn_exp2f(fmaf(Sc[cg][3], 0.18033688f, hp_l + kv.w));
            q01[cg] = pack2t(pe0, pe1);
            q23[cg] = pack2t(pe2, pe3);
        }

        // ---- PV with in-register P-transpose (shfl) ----
        #pragma unroll
        for (int half = 0; half < 2; ++half) {
            const int cgX = half * 2, cgY = half * 2 + 1;
            const int w0A = __shfl((int)q01[cgX], srcA), w0B = __shfl((int)q01[cgY], srcA);
            const int w1A = __shfl((int)q23[cgX], srcA), w1B = __shfl((int)q23[cgY], srcA);
            const int w2A = __shfl((int)q01[cgX], srcB), w2B = __shfl((int)q01[cgY], srcB);
            const int w3A = __shfl((int)q23[cgX], srcB), w3B = __shfl((int)q23[cgY], srcB);
            union { int u[4]; short8 s; } ap;
            ap.u[0] = loq ? w0A : w0B;
            ap.u[1] = loq ? w1A : w1B;
            ap.u[2] = loq ? w2A : w2B;
            ap.u[3] = loq ? w3A : w3B;
            __builtin_amdgcn_s_setprio(1);
            #pragma unroll
            for (int g = 0; g < 4; ++g) {
                const int rv = g * 16 + l16;
                short8 bV = *(const short8*)&Vs[p][rv * 64 + ((quad + half * 4) ^ (rv & 7)) * 8];
                O[g] = __builtin_amdgcn_mfma_f32_16x16x32_bf16(ap.s, bV, O[g], 0, 0, 0);
            }
            O[4] = __builtin_amdgcn_mfma_f32_16x16x32_bf16(ap.s, b1v, O[4], 0, 0, 0);
            __builtin_amdgcn_s_setprio(0);
        }

        __syncthreads();   // next tile ready; all waves done with buf[p]
        p ^= 1;
    }

    // epilogue: l lives in lanes with l16==0 (col 0 of ones output)
    #pragma unroll
    for (int r = 0; r < 4; ++r) {
        const float l  = __shfl(O[4][r], (lane & 48));   // lane quad*16 (l16=0)
        const float rl = 1.f / l;
        const size_t ob = ((size_t)b * S_ + q0 + wid * 16 + quad * 4 + r) * E_ + h * 64;
        #pragma unroll
        for (int g = 0; g < 4; ++g)
            Att[ob + g * 16 + l16] = f2b(O[g][r] * rl);
    }
}

// ---------------------------------------------------------------------------
// Kernel 3: output projection (UNCHANGED).
// ---------------------------------------------------------------------------
__global__ __launch_bounds__(256, 4) void fc_mfma_kernel(
    const ush* __restrict__ Ain, const ush* __restrict__ W,
    const float* __restrict__ bias, float* __restrict__ Out)
{
    __shared__ ush As[64 * 64];    //  8 KB
    __shared__ ush Bs[128 * 64];   // 16 KB

    const int bid0 = blockIdx.x + 64 * blockIdx.y;   // grid (64, 6)
    const int bid  = (bid0 & 7) * 48 + (bid0 >> 3);
    const int bx   = bid & 63;
    const int by   = bid >> 6;

    const int m0 = bx * 64;
    const int n0 = by * 128;
    const int t  = threadIdx.x;
    const int wid  = t >> 6;
    const int lane = t & 63;
    const int quad = lane >> 4;
    const int l16  = lane & 15;
    const int wr  = (wid >> 1) * 32;
    const int wcn = (wid & 1) * 64;
    const int srow = lane >> 3;
    const int schk = lane & 7;

    f32x4 acc[2][4];
    #pragma unroll
    for (int i = 0; i < 2; ++i)
        #pragma unroll
        for (int j = 0; j < 4; ++j) acc[i][j] = (f32x4){0.f, 0.f, 0.f, 0.f};

    for (int kt = 0; kt < E_ / 64; ++kt) {
        const int kb = kt * 64;
        // stage: A 16 rows/wave (2 calls), B 32 rows/wave (4 calls)
        #pragma unroll
        for (int j = 0; j < 2; ++j) {
            const int r = wid * 16 + j * 8 + srow;
            const int c = schk ^ (r & 7);
            GLOAD16(&Ain[(size_t)(m0 + r) * E_ + kb + c * 8], &As[(wid * 16 + j * 8) * 64]);
        }
        #pragma unroll
        for (int j = 0; j < 4; ++j) {
            const int r = wid * 32 + j * 8 + srow;
            const int c = schk ^ (r & 7);
            GLOAD16(&W[(size_t)(n0 + r) * E_ + kb + c * 8], &Bs[(wid * 32 + j * 8) * 64]);
        }
        __syncthreads();

        #pragma unroll
        for (int ks = 0; ks < 2; ++ks) {
            short8 bfr[4];
            #pragma unroll
            for (int nj = 0; nj < 4; ++nj) {
                const int rn = wcn + nj * 16 + l16;
                bfr[nj] = *(const short8*)&Bs[rn * 64 + ((quad + ks * 4) ^ (rn & 7)) * 8];
            }
            #pragma unroll
            for (int mi = 0; mi < 2; ++mi) {
                const int rm = wr + mi * 16 + l16;
                short8 a = *(const short8*)&As[rm * 64 + ((quad + ks * 4) ^ (rm & 7)) * 8];
                #pragma unroll
                for (int nj = 0; nj < 4; ++nj)
                    acc[mi][nj] = __builtin_amdgcn_mfma_f32_16x16x32_bf16(a, bfr[nj], acc[mi][nj], 0, 0, 0);
            }
        }
        __syncthreads();
    }

    #pragma unroll
    for (int nj = 0; nj < 4; ++nj) {
        const int n = n0 + wcn + nj * 16 + l16;
        const float bw = bias[n];
        #pragma unroll
        for (int mi = 0; mi < 2; ++mi)
            #pragma unroll
            for (int r = 0; r < 4; ++r) {
                const int m = m0 + wr + mi * 16 + quad * 4 + r;
                Out[(size_t)m * E_ + n] = acc[mi][nj][r] + bw;
            }
    }
}

// ---------------------------------------------------------------------------
extern "C" void kernel_launch(void* const* d_in, const int* in_sizes, int n_in,
                              void* d_out, int out_size, void* d_ws, size_t ws_size,
                              hipStream_t stream)
{
    const float* q_in  = (const float*)d_in[0];
    const float* k_in  = (const float*)d_in[1];
    const float* v_in  = (const float*)d_in[2];
    const float* pb    = (const float*)d_in[3];
    const int*   mask  = (const int*)d_in[4];
    const float* wq    = (const float*)d_in[5];
    const float* bq    = (const float*)d_in[6];
    const float* wk    = (const float*)d_in[7];
    const float* bk    = (const float*)d_in[8];
    const float* wv    = (const float*)d_in[9];
    const float* bv    = (const float*)d_in[10];
    const float* fw    = (const float*)d_in[11];
    const float* fb    = (const float*)d_in[12];
    const float* coeff = (const float*)d_in[13];
    float* out = (float*)d_out;

    const size_t per = (size_t)B_ * H_ * S_ * D_;   // 3,145,728 elements
    const size_t wel = (size_t)E_ * E_;             //   589,824 elements

    // Workspace layout (~43 MB). Wqb/Wkb/Wvb are contiguous -> Wall[2304][768].
    // Xqb is dead after qkv -> Att aliases it.
    ush* Qb   = (ush*)d_ws;
    ush* Kb   = Qb  + per;
    ush* Vtb  = Kb  + per;
    ush* Xqb  = Vtb + per;
    ush* Xkb  = Xqb + per;
    ush* Xvb  = Xkb + per;
    ush* Wqb  = Xvb + per;                          // == Wall
    ush* Wkb  = Wqb + wel;
    ush* Wvb  = Wkb + wel;
    ush* Wfb  = Wvb + wel;
    float2* rope = (float2*)(Wfb + wel);            // [S][32], 512 KB (8B-aligned)
    ush* Attb = Xqb;                                // alias, live after qkv

    convert_kernel<<<dim3(6016), 256, 0, stream>>>(
        q_in, k_in, v_in, wq, wk, wv, fw,
        Xqb, Xkb, Xvb, Wqb, Wkb, Wvb, Wfb, rope);

    qkv_mfma_kernel<<<dim3(32, 18), 256, 0, stream>>>(
        Xqb, Xkb, Xvb, Wqb, bq, bk, bv, rope, Qb, Kb, Vtb);

    attn_kernel<<<dim3(S_ / 64, H_, B_), 256, 0, stream>>>(
        Qb, Kb, Vtb, pb, mask, coeff, Attb);

    fc_mfma_kernel<<<dim3(64, 6), 256, 0, stream>>>(Attb, Wfb, fb, out);
}

// Round 12
// 203.136 us; speedup vs baseline: 1.0282x; 1.0282x over previous
//
#include <hip/hip_runtime.h>
#include <math.h>

#define B_ 2
#define S_ 2048
#define E_ 768
#define H_ 12
#define D_ 64
#define M_ (B_*S_)   // 4096 rows total

typedef unsigned short ush;
using short8 = __attribute__((ext_vector_type(8))) short;   // 8 bf16 (4 VGPRs)
using f32x4  = __attribute__((ext_vector_type(4))) float;   // MFMA C/D

__device__ __forceinline__ ush f2b(float x) {               // fp32 -> bf16 RNE
    union { float f; unsigned u; } v; v.f = x;
    unsigned r = v.u + 0x7fffu + ((v.u >> 16) & 1u);
    return (ush)(r >> 16);
}
// fp32 pair -> packed bf16: round-half-up + v_perm_b32 (3 VALU ops).
__device__ __forceinline__ unsigned pack2(float x, float y) {
    unsigned bx = __float_as_uint(x) + 0x8000u;
    unsigned by = __float_as_uint(y) + 0x8000u;
    return __builtin_amdgcn_perm(by, bx, 0x07060302u);  // [bx.hi16 | by.hi16<<16]
}

// async global->LDS, 16B/lane. LDS dest = wave-uniform base + lane*16 (linear).
// Swizzled LDS content via permuted per-lane GLOBAL source (rule 21; XOR is
// an involution): physical chunk (lane&7) of row r holds logical chunk
// (lane&7)^(r&7); reads XOR the chunk index with (r&7).
#define GLOAD16(gp, lp) __builtin_amdgcn_global_load_lds( \
    (const __attribute__((address_space(1))) void*)(gp),   \
    (__attribute__((address_space(3))) void*)(lp), 16, 0, 0)

// ---------------------------------------------------------------------------
// Kernel 0: one-time fp32->bf16 convert (q,k,v inputs + 4 weight matrices)
// and RoPE cos/sin table [S][32] float2. UNCHANGED.
// ---------------------------------------------------------------------------
__global__ __launch_bounds__(256) void convert_kernel(
    const float* __restrict__ q, const float* __restrict__ k, const float* __restrict__ v,
    const float* __restrict__ wq, const float* __restrict__ wk,
    const float* __restrict__ wv, const float* __restrict__ fw,
    ush* __restrict__ Xq, ush* __restrict__ Xk, ush* __restrict__ Xv,
    ush* __restrict__ Wqb, ush* __restrict__ Wkb, ush* __restrict__ Wvb,
    ush* __restrict__ Wfb, float2* __restrict__ rope)
{
    const int bid = blockIdx.x;
    const int t   = threadIdx.x;
    if (bid < 4608) {                         // 3 inputs, 1536 blocks each
        const int tz = bid / 1536, off = bid % 1536;
        const float* __restrict__ src = (tz == 0) ? q : (tz == 1) ? k : v;
        ush* __restrict__ dst = (tz == 0) ? Xq : (tz == 1) ? Xk : Xv;
        const size_t base = ((size_t)off * 256 + t) * 8;
        const float4 a = *(const float4*)&src[base];
        const float4 b = *(const float4*)&src[base + 4];
        uint4 o;
        o.x = pack2(a.x, a.y); o.y = pack2(a.z, a.w);
        o.z = pack2(b.x, b.y); o.w = pack2(b.z, b.w);
        *(uint4*)&dst[base] = o;
    } else if (bid < 5760) {                  // 4 weights, 288 blocks each
        const int id = bid - 4608;
        const int tz = id / 288, off = id % 288;
        const float* __restrict__ src = (tz == 0) ? wq : (tz == 1) ? wk : (tz == 2) ? wv : fw;
        ush* __restrict__ dst = (tz == 0) ? Wqb : (tz == 1) ? Wkb : (tz == 2) ? Wvb : Wfb;
        const size_t base = ((size_t)off * 256 + t) * 8;
        const float4 a = *(const float4*)&src[base];
        const float4 b = *(const float4*)&src[base + 4];
        uint4 o;
        o.x = pack2(a.x, a.y); o.y = pack2(a.z, a.w);
        o.z = pack2(b.x, b.y); o.w = pack2(b.z, b.w);
        *(uint4*)&dst[base] = o;
    } else {                                  // rope table: 65536 entries
        const int idx = (bid - 5760) * 256 + t;
        const int s = idx >> 5, dp = idx & 31;
        const float invf = expf(-(float)dp * (9.210340371976184f / 32.f)); // 10000^(-dp/32)
        float sn, cs;
        sincosf((float)s * invf, &sn, &cs);
        rope[idx] = make_float2(cs, sn);
    }
}

// ---------------------------------------------------------------------------
// Kernel 1: FUSED QKV projection. UNCHANGED (frozen since R4).
// ---------------------------------------------------------------------------
__global__ __launch_bounds__(256, 4) void qkv_mfma_kernel(
    const ush* __restrict__ Xq, const ush* __restrict__ Xk, const ush* __restrict__ Xv,
    const ush* __restrict__ Wall,
    const float* __restrict__ bq, const float* __restrict__ bk, const float* __restrict__ bv,
    const float2* __restrict__ rope,
    ush* __restrict__ Qb, ush* __restrict__ Kb, ush* __restrict__ Vtb)
{
    __shared__ ush As[128 * 64];   // [m][k], chunk-swizzled, 16 KB
    __shared__ ush Bs[128 * 64];   // [n][k], chunk-swizzled, 16 KB

    // bijective XCD swizzle: 576 blocks = 8 XCDs x 72 contiguous
    const int bid0 = blockIdx.x + 32 * blockIdx.y;
    const int bid  = (bid0 & 7) * 72 + (bid0 >> 3);
    const int bx   = bid & 31;                 // m-block 0..31
    const int by   = bid >> 5;                 // n-block 0..17

    const int z   = by / 6;                    // 0=Q 1=K 2=V
    const int byz = by - z * 6;                // n-block within z
    const int n0  = by * 128;                  // row in Wall
    const ush* __restrict__ X = (z == 0) ? Xq : (z == 1) ? Xk : Xv;
    const float* __restrict__ bias = (z == 0) ? bq : (z == 1) ? bk : bv;

    const int m0 = bx * 128;
    const int t  = threadIdx.x;
    const int wid  = t >> 6;
    const int lane = t & 63;
    const int quad = lane >> 4;
    const int l16  = lane & 15;
    const int wr  = (wid >> 1) * 64;           // wave row offset (0/64)
    const int wcn = (wid & 1) * 64;            // wave col offset (0/64)
    const int h   = byz * 2 + (wid & 1);       // this wave's head (0..11)
    const int srow = lane >> 3;                // staging row within 8-row group
    const int schk = lane & 7;                 // staging physical 16B chunk

    f32x4 acc[4][4];
    #pragma unroll
    for (int i = 0; i < 4; ++i)
        #pragma unroll
        for (int j = 0; j < 4; ++j) acc[i][j] = (f32x4){0.f, 0.f, 0.f, 0.f};

    for (int kt = 0; kt < E_ / 64; ++kt) {
        const int kb = kt * 64;
        // stage: each wave 32 A-rows + 32 B-rows (8 gload/thread)
        #pragma unroll
        for (int j = 0; j < 4; ++j) {
            const int r = wid * 32 + j * 8 + srow;
            const int c = schk ^ (r & 7);
            GLOAD16(&X[(size_t)(m0 + r) * E_ + kb + c * 8], &As[(wid * 32 + j * 8) * 64]);
            GLOAD16(&Wall[(size_t)(n0 + r) * E_ + kb + c * 8], &Bs[(wid * 32 + j * 8) * 64]);
        }
        __syncthreads();   // vmcnt drained -> tile visible (TLP across blocks hides)

        #pragma unroll
        for (int ks = 0; ks < 2; ++ks) {
            short8 bfr[4];
            #pragma unroll
            for (int nj = 0; nj < 4; ++nj) {
                const int rn = wcn + nj * 16 + l16;
                bfr[nj] = *(const short8*)&Bs[rn * 64 + ((quad + ks * 4) ^ (rn & 7)) * 8];
            }
            #pragma unroll
            for (int mi = 0; mi < 4; ++mi) {
                const int rm = wr + mi * 16 + l16;
                short8 a = *(const short8*)&As[rm * 64 + ((quad + ks * 4) ^ (rm & 7)) * 8];
                #pragma unroll
                for (int nj = 0; nj < 4; ++nj)
                    acc[mi][nj] = __builtin_amdgcn_mfma_f32_16x16x32_bf16(a, bfr[nj], acc[mi][nj], 0, 0, 0);
            }
        }
        __syncthreads();   // all reads done before next tile overwrite
    }

    // ---- epilogue (per-wave head h; cols d = nj*16+l16 in [0,64)) ----
    if (z < 2) {
        ush* __restrict__ Ob = (z == 0) ? Qb : Kb;
        const bool even = (l16 & 1) == 0;
        #pragma unroll
        for (int nj = 0; nj < 4; ++nj) {
            const int d = nj * 16 + l16;
            const float bw = bias[h * 64 + d];
            #pragma unroll
            for (int mi = 0; mi < 4; ++mi) {
                #pragma unroll
                for (int r = 0; r < 4; ++r) {
                    const int m = m0 + wr + mi * 16 + quad * 4 + r;
                    const int bb = m >> 11, s = m & (S_ - 1);
                    const float v = acc[mi][nj][r] + bw;
                    const float vp = __shfl_xor(v, 1);           // partner (d^1)
                    if (even) {                                  // even lane stores the pair
                        const float2 cs2 = rope[s * 32 + (d >> 1)];
                        const float re = v  * cs2.x - vp * cs2.y;
                        const float ro = vp * cs2.x + v  * cs2.y;
                        const size_t o = (((size_t)bb * H_ + h) * S_ + s) * (size_t)D_ + d;
                        *(unsigned*)&Ob[o] = pack2(re, ro);
                    }
                }
            }
        }
    } else {
        // V: per-wave 64x64 LDS transpose (chunk-XOR swizzled, pitch 64),
        // then 128B-contiguous uint4 stores of V^T rows. Wave-private region:
        // waves 0,1 use As halves; waves 2,3 use Bs halves (both dead now).
        ush* Tb = (wid < 2) ? &As[wid * 4096] : &Bs[(wid - 2) * 4096];
        #pragma unroll
        for (int nj = 0; nj < 4; ++nj) {
            const int d = nj * 16 + l16;
            const float bw = bias[h * 64 + d];
            const int g = (d & 7) << 3;
            #pragma unroll
            for (int mi = 0; mi < 4; ++mi) {
                const int s_l = mi * 16 + quad * 4;
                const int sx  = s_l ^ g;       // XOR touches bits>=3 only; pair stays aligned
                *(unsigned*)&Tb[d * 64 + sx]     = pack2(acc[mi][nj][0] + bw, acc[mi][nj][1] + bw);
                *(unsigned*)&Tb[d * 64 + sx + 2] = pack2(acc[mi][nj][2] + bw, acc[mi][nj][3] + bw);
            }
        }
        __syncthreads();
        const int bb = (m0 + wr) >> 11;
        const int sb = (m0 + wr) & (S_ - 1);
        #pragma unroll
        for (int i = 0; i < 8; ++i) {
            const int d2 = (lane >> 3) + i * 8;
            const int c2 = lane & 7;
            const uint4 val = *(const uint4*)&Tb[d2 * 64 + ((c2 ^ (d2 & 7)) * 8)];
            const size_t o = (((size_t)bb * H_ + h) * D_ + d2) * (size_t)S_ + sb + c2 * 8;
            *(uint4*)&Vtb[o] = val;
        }
    }
}

// ---------------------------------------------------------------------------
// Kernel 2: MFMA flash attention — R8 version (best measured: 59.2 us).
// R9/R10 post-mortem: the shfl-based P-transpose regressed because
// (1) occupancy is GRID-capped at 3 blocks/CU (768 blocks / 256 CU) so the
// LDS cut could not add blocks, and (2) __shfl lowers to ds_bpermute — an
// LDS-pipe op — so the "in-register" transpose moved MORE traffic through
// the LDS pipe than the Ps round-trip it replaced (conflicts 786K -> 3.15M).
// R8 structure: unswapped QK^T, Ps LDS round-trip (wave-private, no barrier),
// register ones-frag, kbv hoist, softmax/PV ks-interleave, T5 setprio, exp2.
// ---------------------------------------------------------------------------
__global__ __launch_bounds__(256) void attn_kernel(
    const ush* __restrict__ Qb, const ush* __restrict__ Kb, const ush* __restrict__ Vtb,
    const float* __restrict__ pb, const int* __restrict__ mask, const float* __restrict__ coeff,
    ush* __restrict__ Att)
{
    __shared__ ush  Ks[2][64 * 64];    // ping-pong [key][d], chunk-swizzled
    __shared__ ush  Vs[2][64 * 64];    // ping-pong [d][key], chunk-swizzled
    __shared__ ush  Ps[64 * 72];       // P rows [q][key] (wave-private)
    __shared__ float kb_all[S_];       // per-key bias (pre-scaled by log2e)

    const int q0 = blockIdx.x * 64;
    const int h  = blockIdx.y;
    const int b  = blockIdx.z;
    const int t  = threadIdx.x;
    const int wid = t >> 6;
    const int lane = t & 63;
    const int quad = lane >> 4;
    const int l16  = lane & 15;
    const int srow = lane >> 3;
    const int schk = lane & 7;

    const int bh = b * H_ + h;
    const float ch = coeff[h];
    const float LOG2E = 1.44269504f;

    // per-key bias for the whole row: ((mask?0:-1e30) - ch*pb[k]) * log2e
    #pragma unroll
    for (int i = 0; i < 8; ++i) {
        const int idx = t + i * 256;
        const int gi = b * S_ + idx;
        kb_all[idx] = ((mask[gi] ? 0.f : -1e30f) - ch * pb[gi]) * LOG2E;
    }

    // register ones B-frag: output col 0 = 1.0, rest 0 (row-sum column)
    short8 b1v;
    {
        const short v1 = (l16 == 0) ? (short)0x3F80 : (short)0;
        b1v = (short8){v1, v1, v1, v1, v1, v1, v1, v1};
    }

    const int qrow = q0 + wid * 16 + l16;
    short8 aQ[2];
    #pragma unroll
    for (int ks = 0; ks < 2; ++ks)
        aQ[ks] = *(const short8*)&Qb[((size_t)bh * S_ + qrow) * D_ + quad * 8 + ks * 32];

    float hp[4];
    #pragma unroll
    for (int r = 0; r < 4; ++r)
        hp[r] = ch * pb[b * S_ + q0 + wid * 16 + quad * 4 + r] * LOG2E;

    f32x4 O[5];                        // O[4] = row-sum accumulator (ones frag)
    #pragma unroll
    for (int g = 0; g < 5; ++g) O[g] = (f32x4){0.f, 0.f, 0.f, 0.f};

    // prologue: stage tile 0 into buffer 0
    #pragma unroll
    for (int j = 0; j < 2; ++j) {
        const int r8 = wid * 16 + j * 8;
        const int r  = r8 + srow;
        const int c  = schk ^ (r & 7);
        GLOAD16(&Kb[((size_t)bh * S_ + r) * D_ + c * 8], &Ks[0][r8 * 64]);
        GLOAD16(&Vtb[((size_t)bh * D_ + r) * S_ + c * 8], &Vs[0][r8 * 64]);
    }
    __syncthreads();   // drains vmcnt; also orders kb_all init

    int p = 0;
    for (int kt = 0; kt < S_ / 64; ++kt) {
        // issue next tile's loads (latency hides under QK/softmax/PV)
        if (kt + 1 < S_ / 64) {
            const int kn = (kt + 1) * 64;
            #pragma unroll
            for (int j = 0; j < 2; ++j) {
                const int r8 = wid * 16 + j * 8;
                const int r  = r8 + srow;
                const int c  = schk ^ (r & 7);
                GLOAD16(&Kb[((size_t)bh * S_ + kn + r) * D_ + c * 8], &Ks[p ^ 1][r8 * 64]);
                GLOAD16(&Vtb[((size_t)bh * D_ + r) * S_ + kn + c * 8], &Vs[p ^ 1][r8 * 64]);
            }
        }

        // kbv early (lgkm overlap with QK MFMAs)
        float kbv[4];
        #pragma unroll
        for (int cg = 0; cg < 4; ++cg) kbv[cg] = kb_all[kt * 64 + cg * 16 + l16];

        // ---- QK^T ---- (T5: prioritize the MFMA cluster)
        f32x4 Sc[4];
        #pragma unroll
        for (int cg = 0; cg < 4; ++cg) Sc[cg] = (f32x4){0.f, 0.f, 0.f, 0.f};
        __builtin_amdgcn_s_setprio(1);
        #pragma unroll
        for (int ks = 0; ks < 2; ++ks) {
            #pragma unroll
            for (int cg = 0; cg < 4; ++cg) {
                const int rk = cg * 16 + l16;
                short8 bK = *(const short8*)&Ks[p][rk * 64 + ((quad + ks * 4) ^ (rk & 7)) * 8];
                Sc[cg] = __builtin_amdgcn_mfma_f32_16x16x32_bf16(aQ[ks], bK, Sc[cg], 0, 0, 0);
            }
        }
        __builtin_amdgcn_s_setprio(0);

        // ---- softmax + PV interleaved by ks-half ----
        // half=0: write Ps cols 0..31 (cg 0,1) then PV ks=0 (reads cols 0..31)
        // half=1: write Ps cols 32..63 (cg 2,3) then PV ks=1
        #pragma unroll
        for (int half = 0; half < 2; ++half) {
            #pragma unroll
            for (int cgi = 0; cgi < 2; ++cgi) {
                const int cg = half * 2 + cgi;
                #pragma unroll
                for (int r = 0; r < 4; ++r) {
                    float s = fmaf(Sc[cg][r], 0.18033688f, hp[r] + kbv[cg]);
                    float pe = __builtin_amdgcn_exp2f(s);  // masked: -> 0
                    Ps[(wid * 16 + quad * 4 + r) * 72 + cg * 16 + l16] =
                        (ush)(__float_as_uint(pe) >> 16);
                }
            }
            // PV for this half (aP reads only the cols written above;
            // same-wave lgkm ordering suffices — Ps rows are wave-private)
            short8 aP = *(const short8*)&Ps[(wid * 16 + l16) * 72 + quad * 8 + half * 32];
            __builtin_amdgcn_s_setprio(1);
            #pragma unroll
            for (int g = 0; g < 4; ++g) {
                const int rv = g * 16 + l16;
                short8 bV = *(const short8*)&Vs[p][rv * 64 + ((quad + half * 4) ^ (rv & 7)) * 8];
                O[g] = __builtin_amdgcn_mfma_f32_16x16x32_bf16(aP, bV, O[g], 0, 0, 0);
            }
            O[4] = __builtin_amdgcn_mfma_f32_16x16x32_bf16(aP, b1v, O[4], 0, 0, 0);
            __builtin_amdgcn_s_setprio(0);
        }

        __syncthreads();   // next tile ready; all waves done with buf[p]
        p ^= 1;
    }

    // epilogue: l lives in lanes with l16==0 (col 0 of ones output)
    #pragma unroll
    for (int r = 0; r < 4; ++r) {
        const float l  = __shfl(O[4][r], (lane & 48));   // lane quad*16 (l16=0)
        const float rl = 1.f / l;
        const size_t ob = ((size_t)b * S_ + q0 + wid * 16 + quad * 4 + r) * E_ + h * 64;
        #pragma unroll
        for (int g = 0; g < 4; ++g)
            Att[ob + g * 16 + l16] = f2b(O[g][r] * rl);
    }
}

// ---------------------------------------------------------------------------
// Kernel 3: output projection (UNCHANGED, frozen since R4).
// ---------------------------------------------------------------------------
__global__ __launch_bounds__(256, 4) void fc_mfma_kernel(
    const ush* __restrict__ Ain, const ush* __restrict__ W,
    const float* __restrict__ bias, float* __restrict__ Out)
{
    __shared__ ush As[64 * 64];    //  8 KB
    __shared__ ush Bs[128 * 64];   // 16 KB

    const int bid0 = blockIdx.x + 64 * blockIdx.y;   // grid (64, 6)
    const int bid  = (bid0 & 7) * 48 + (bid0 >> 3);
    const int bx   = bid & 63;
    const int by   = bid >> 6;

    const int m0 = bx * 64;
    const int n0 = by * 128;
    const int t  = threadIdx.x;
    const int wid  = t >> 6;
    const int lane = t & 63;
    const int quad = lane >> 4;
    const int l16  = lane & 15;
    const int wr  = (wid >> 1) * 32;
    const int wcn = (wid & 1) * 64;
    const int srow = lane >> 3;
    const int schk = lane & 7;

    f32x4 acc[2][4];
    #pragma unroll
    for (int i = 0; i < 2; ++i)
        #pragma unroll
        for (int j = 0; j < 4; ++j) acc[i][j] = (f32x4){0.f, 0.f, 0.f, 0.f};

    for (int kt = 0; kt < E_ / 64; ++kt) {
        const int kb = kt * 64;
        // stage: A 16 rows/wave (2 calls), B 32 rows/wave (4 calls)
        #pragma unroll
        for (int j = 0; j < 2; ++j) {
            const int r = wid * 16 + j * 8 + srow;
            const int c = schk ^ (r & 7);
            GLOAD16(&Ain[(size_t)(m0 + r) * E_ + kb + c * 8], &As[(wid * 16 + j * 8) * 64]);
        }
        #pragma unroll
        for (int j = 0; j < 4; ++j) {
            const int r = wid * 32 + j * 8 + srow;
            const int c = schk ^ (r & 7);
            GLOAD16(&W[(size_t)(n0 + r) * E_ + kb + c * 8], &Bs[(wid * 32 + j * 8) * 64]);
        }
        __syncthreads();

        #pragma unroll
        for (int ks = 0; ks < 2; ++ks) {
            short8 bfr[4];
            #pragma unroll
            for (int nj = 0; nj < 4; ++nj) {
                const int rn = wcn + nj * 16 + l16;
                bfr[nj] = *(const short8*)&Bs[rn * 64 + ((quad + ks * 4) ^ (rn & 7)) * 8];
            }
            #pragma unroll
            for (int mi = 0; mi < 2; ++mi) {
                const int rm = wr + mi * 16 + l16;
                short8 a = *(const short8*)&As[rm * 64 + ((quad + ks * 4) ^ (rm & 7)) * 8];
                #pragma unroll
                for (int nj = 0; nj < 4; ++nj)
                    acc[mi][nj] = __builtin_amdgcn_mfma_f32_16x16x32_bf16(a, bfr[nj], acc[mi][nj], 0, 0, 0);
            }
        }
        __syncthreads();
    }

    #pragma unroll
    for (int nj = 0; nj < 4; ++nj) {
        const int n = n0 + wcn + nj * 16 + l16;
        const float bw = bias[n];
        #pragma unroll
        for (int mi = 0; mi < 2; ++mi)
            #pragma unroll
            for (int r = 0; r < 4; ++r) {
                const int m = m0 + wr + mi * 16 + quad * 4 + r;
                Out[(size_t)m * E_ + n] = acc[mi][nj][r] + bw;
            }
    }
}

// ---------------------------------------------------------------------------
extern "C" void kernel_launch(void* const* d_in, const int* in_sizes, int n_in,
                              void* d_out, int out_size, void* d_ws, size_t ws_size,
                              hipStream_t stream)
{
    const float* q_in  = (const float*)d_in[0];
    const float* k_in  = (const float*)d_in[1];
    const float* v_in  = (const float*)d_in[2];
    const float* pb    = (const float*)d_in[3];
    const int*   mask  = (const int*)d_in[4];
    const float* wq    = (const float*)d_in[5];
    const float* bq    = (const float*)d_in[6];
    const float* wk    = (const float*)d_in[7];
    const float* bk    = (const float*)d_in[8];
    const float* wv    = (const float*)d_in[9];
    const float* bv    = (const float*)d_in[10];
    const float* fw    = (const float*)d_in[11];
    const float* fb    = (const float*)d_in[12];
    const float* coeff = (const float*)d_in[13];
    float* out = (float*)d_out;

    const size_t per = (size_t)B_ * H_ * S_ * D_;   // 3,145,728 elements
    const size_t wel = (size_t)E_ * E_;             //   589,824 elements

    // Workspace layout (~43 MB). Wqb/Wkb/Wvb are contiguous -> Wall[2304][768].
    // Xqb is dead after qkv -> Att aliases it.
    ush* Qb   = (ush*)d_ws;
    ush* Kb   = Qb  + per;
    ush* Vtb  = Kb  + per;
    ush* Xqb  = Vtb + per;
    ush* Xkb  = Xqb + per;
    ush* Xvb  = Xkb + per;
    ush* Wqb  = Xvb + per;                          // == Wall
    ush* Wkb  = Wqb + wel;
    ush* Wvb  = Wkb + wel;
    ush* Wfb  = Wvb + wel;
    float2* rope = (float2*)(Wfb + wel);            // [S][32], 512 KB (8B-aligned)
    ush* Attb = Xqb;                                // alias, live after qkv

    convert_kernel<<<dim3(6016), 256, 0, stream>>>(
        q_in, k_in, v_in, wq, wk, wv, fw,
        Xqb, Xkb, Xvb, Wqb, Wkb, Wvb, Wfb, rope);

    qkv_mfma_kernel<<<dim3(32, 18), 256, 0, stream>>>(
        Xqb, Xkb, Xvb, Wqb, bq, bk, bv, rope, Qb, Kb, Vtb);

    attn_kernel<<<dim3(S_ / 64, H_, B_), 256, 0, stream>>>(
        Qb, Kb, Vtb, pb, mask, coeff, Attb);

    fc_mfma_kernel<<<dim3(64, 6), 256, 0, stream>>>(Attb, Wfb, fb, out);
}

// Round 13
// 203.007 us; speedup vs baseline: 1.0289x; 1.0006x over previous
//
#include <hip/hip_runtime.h>
#include <math.h>

#define B_ 2
#define S_ 2048
#define E_ 768
#define H_ 12
#define D_ 64
#define M_ (B_*S_)   // 4096 rows total

typedef unsigned short ush;
using short8 = __attribute__((ext_vector_type(8))) short;   // 8 bf16 (4 VGPRs)
using f32x4  = __attribute__((ext_vector_type(4))) float;   // MFMA C/D

__device__ __forceinline__ ush f2b(float x) {               // fp32 -> bf16 RNE
    union { float f; unsigned u; } v; v.f = x;
    unsigned r = v.u + 0x7fffu + ((v.u >> 16) & 1u);
    return (ush)(r >> 16);
}
// fp32 pair -> packed bf16: round-half-up + v_perm_b32 (3 VALU ops).
__device__ __forceinline__ unsigned pack2(float x, float y) {
    unsigned bx = __float_as_uint(x) + 0x8000u;
    unsigned by = __float_as_uint(y) + 0x8000u;
    return __builtin_amdgcn_perm(by, bx, 0x07060302u);  // [bx.hi16 | by.hi16<<16]
}

// async global->LDS, 16B/lane. LDS dest = wave-uniform base + lane*16 (linear).
// Swizzled LDS content via permuted per-lane GLOBAL source (rule 21; XOR is
// an involution): physical chunk (lane&7) of row r holds logical chunk
// (lane&7)^(r&7); reads XOR the chunk index with (r&7).
#define GLOAD16(gp, lp) __builtin_amdgcn_global_load_lds( \
    (const __attribute__((address_space(1))) void*)(gp),   \
    (__attribute__((address_space(3))) void*)(lp), 16, 0, 0)

// ---------------------------------------------------------------------------
// Kernel 0: one-time fp32->bf16 convert (q,k,v inputs + 4 weight matrices)
// and RoPE cos/sin table [S][32] float2. UNCHANGED.
// ---------------------------------------------------------------------------
__global__ __launch_bounds__(256) void convert_kernel(
    const float* __restrict__ q, const float* __restrict__ k, const float* __restrict__ v,
    const float* __restrict__ wq, const float* __restrict__ wk,
    const float* __restrict__ wv, const float* __restrict__ fw,
    ush* __restrict__ Xq, ush* __restrict__ Xk, ush* __restrict__ Xv,
    ush* __restrict__ Wqb, ush* __restrict__ Wkb, ush* __restrict__ Wvb,
    ush* __restrict__ Wfb, float2* __restrict__ rope)
{
    const int bid = blockIdx.x;
    const int t   = threadIdx.x;
    if (bid < 4608) {                         // 3 inputs, 1536 blocks each
        const int tz = bid / 1536, off = bid % 1536;
        const float* __restrict__ src = (tz == 0) ? q : (tz == 1) ? k : v;
        ush* __restrict__ dst = (tz == 0) ? Xq : (tz == 1) ? Xk : Xv;
        const size_t base = ((size_t)off * 256 + t) * 8;
        const float4 a = *(const float4*)&src[base];
        const float4 b = *(const float4*)&src[base + 4];
        uint4 o;
        o.x = pack2(a.x, a.y); o.y = pack2(a.z, a.w);
        o.z = pack2(b.x, b.y); o.w = pack2(b.z, b.w);
        *(uint4*)&dst[base] = o;
    } else if (bid < 5760) {                  // 4 weights, 288 blocks each
        const int id = bid - 4608;
        const int tz = id / 288, off = id % 288;
        const float* __restrict__ src = (tz == 0) ? wq : (tz == 1) ? wk : (tz == 2) ? wv : fw;
        ush* __restrict__ dst = (tz == 0) ? Wqb : (tz == 1) ? Wkb : (tz == 2) ? Wvb : Wfb;
        const size_t base = ((size_t)off * 256 + t) * 8;
        const float4 a = *(const float4*)&src[base];
        const float4 b = *(const float4*)&src[base + 4];
        uint4 o;
        o.x = pack2(a.x, a.y); o.y = pack2(a.z, a.w);
        o.z = pack2(b.x, b.y); o.w = pack2(b.z, b.w);
        *(uint4*)&dst[base] = o;
    } else {                                  // rope table: 65536 entries
        const int idx = (bid - 5760) * 256 + t;
        const int s = idx >> 5, dp = idx & 31;
        const float invf = expf(-(float)dp * (9.210340371976184f / 32.f)); // 10000^(-dp/32)
        float sn, cs;
        sincosf((float)s * invf, &sn, &cs);
        rope[idx] = make_float2(cs, sn);
    }
}

// ---------------------------------------------------------------------------
// Kernel 1: FUSED QKV projection. UNCHANGED (frozen since R4).
// ---------------------------------------------------------------------------
__global__ __launch_bounds__(256, 4) void qkv_mfma_kernel(
    const ush* __restrict__ Xq, const ush* __restrict__ Xk, const ush* __restrict__ Xv,
    const ush* __restrict__ Wall,
    const float* __restrict__ bq, const float* __restrict__ bk, const float* __restrict__ bv,
    const float2* __restrict__ rope,
    ush* __restrict__ Qb, ush* __restrict__ Kb, ush* __restrict__ Vtb)
{
    __shared__ ush As[128 * 64];   // [m][k], chunk-swizzled, 16 KB
    __shared__ ush Bs[128 * 64];   // [n][k], chunk-swizzled, 16 KB

    // bijective XCD swizzle: 576 blocks = 8 XCDs x 72 contiguous
    const int bid0 = blockIdx.x + 32 * blockIdx.y;
    const int bid  = (bid0 & 7) * 72 + (bid0 >> 3);
    const int bx   = bid & 31;                 // m-block 0..31
    const int by   = bid >> 5;                 // n-block 0..17

    const int z   = by / 6;                    // 0=Q 1=K 2=V
    const int byz = by - z * 6;                // n-block within z
    const int n0  = by * 128;                  // row in Wall
    const ush* __restrict__ X = (z == 0) ? Xq : (z == 1) ? Xk : Xv;
    const float* __restrict__ bias = (z == 0) ? bq : (z == 1) ? bk : bv;

    const int m0 = bx * 128;
    const int t  = threadIdx.x;
    const int wid  = t >> 6;
    const int lane = t & 63;
    const int quad = lane >> 4;
    const int l16  = lane & 15;
    const int wr  = (wid >> 1) * 64;           // wave row offset (0/64)
    const int wcn = (wid & 1) * 64;            // wave col offset (0/64)
    const int h   = byz * 2 + (wid & 1);       // this wave's head (0..11)
    const int srow = lane >> 3;                // staging row within 8-row group
    const int schk = lane & 7;                 // staging physical 16B chunk

    f32x4 acc[4][4];
    #pragma unroll
    for (int i = 0; i < 4; ++i)
        #pragma unroll
        for (int j = 0; j < 4; ++j) acc[i][j] = (f32x4){0.f, 0.f, 0.f, 0.f};

    for (int kt = 0; kt < E_ / 64; ++kt) {
        const int kb = kt * 64;
        // stage: each wave 32 A-rows + 32 B-rows (8 gload/thread)
        #pragma unroll
        for (int j = 0; j < 4; ++j) {
            const int r = wid * 32 + j * 8 + srow;
            const int c = schk ^ (r & 7);
            GLOAD16(&X[(size_t)(m0 + r) * E_ + kb + c * 8], &As[(wid * 32 + j * 8) * 64]);
            GLOAD16(&Wall[(size_t)(n0 + r) * E_ + kb + c * 8], &Bs[(wid * 32 + j * 8) * 64]);
        }
        __syncthreads();   // vmcnt drained -> tile visible (TLP across blocks hides)

        #pragma unroll
        for (int ks = 0; ks < 2; ++ks) {
            short8 bfr[4];
            #pragma unroll
            for (int nj = 0; nj < 4; ++nj) {
                const int rn = wcn + nj * 16 + l16;
                bfr[nj] = *(const short8*)&Bs[rn * 64 + ((quad + ks * 4) ^ (rn & 7)) * 8];
            }
            #pragma unroll
            for (int mi = 0; mi < 4; ++mi) {
                const int rm = wr + mi * 16 + l16;
                short8 a = *(const short8*)&As[rm * 64 + ((quad + ks * 4) ^ (rm & 7)) * 8];
                #pragma unroll
                for (int nj = 0; nj < 4; ++nj)
                    acc[mi][nj] = __builtin_amdgcn_mfma_f32_16x16x32_bf16(a, bfr[nj], acc[mi][nj], 0, 0, 0);
            }
        }
        __syncthreads();   // all reads done before next tile overwrite
    }

    // ---- epilogue (per-wave head h; cols d = nj*16+l16 in [0,64)) ----
    if (z < 2) {
        ush* __restrict__ Ob = (z == 0) ? Qb : Kb;
        const bool even = (l16 & 1) == 0;
        #pragma unroll
        for (int nj = 0; nj < 4; ++nj) {
            const int d = nj * 16 + l16;
            const float bw = bias[h * 64 + d];
            #pragma unroll
            for (int mi = 0; mi < 4; ++mi) {
                #pragma unroll
                for (int r = 0; r < 4; ++r) {
                    const int m = m0 + wr + mi * 16 + quad * 4 + r;
                    const int bb = m >> 11, s = m & (S_ - 1);
                    const float v = acc[mi][nj][r] + bw;
                    const float vp = __shfl_xor(v, 1);           // partner (d^1)
                    if (even) {                                  // even lane stores the pair
                        const float2 cs2 = rope[s * 32 + (d >> 1)];
                        const float re = v  * cs2.x - vp * cs2.y;
                        const float ro = vp * cs2.x + v  * cs2.y;
                        const size_t o = (((size_t)bb * H_ + h) * S_ + s) * (size_t)D_ + d;
                        *(unsigned*)&Ob[o] = pack2(re, ro);
                    }
                }
            }
        }
    } else {
        // V: per-wave 64x64 LDS transpose (chunk-XOR swizzled, pitch 64),
        // then 128B-contiguous uint4 stores of V^T rows. Wave-private region:
        // waves 0,1 use As halves; waves 2,3 use Bs halves (both dead now).
        ush* Tb = (wid < 2) ? &As[wid * 4096] : &Bs[(wid - 2) * 4096];
        #pragma unroll
        for (int nj = 0; nj < 4; ++nj) {
            const int d = nj * 16 + l16;
            const float bw = bias[h * 64 + d];
            const int g = (d & 7) << 3;
            #pragma unroll
            for (int mi = 0; mi < 4; ++mi) {
                const int s_l = mi * 16 + quad * 4;
                const int sx  = s_l ^ g;       // XOR touches bits>=3 only; pair stays aligned
                *(unsigned*)&Tb[d * 64 + sx]     = pack2(acc[mi][nj][0] + bw, acc[mi][nj][1] + bw);
                *(unsigned*)&Tb[d * 64 + sx + 2] = pack2(acc[mi][nj][2] + bw, acc[mi][nj][3] + bw);
            }
        }
        __syncthreads();
        const int bb = (m0 + wr) >> 11;
        const int sb = (m0 + wr) & (S_ - 1);
        #pragma unroll
        for (int i = 0; i < 8; ++i) {
            const int d2 = (lane >> 3) + i * 8;
            const int c2 = lane & 7;
            const uint4 val = *(const uint4*)&Tb[d2 * 64 + ((c2 ^ (d2 & 7)) * 8)];
            const size_t o = (((size_t)bb * H_ + h) * D_ + d2) * (size_t)S_ + sb + c2 * 8;
            *(uint4*)&Vtb[o] = val;
        }
    }
}

// ---------------------------------------------------------------------------
// Kernel 2: MFMA flash attention — R8 structure (best measured). R13 change
// (ONLY change this round): XCD-LOCALITY REMAP of block roles. Default
// (q,h,b) grid round-robins the 32 q-blocks of one (b,h) across all 8 XCDs,
// so every per-XCD L2 pulls the full 512 KB K/V -> FETCH 52 MB (2.5x the
// unique inputs). Remap (bijective, 768 = 8 xcd x 3 bh x 32 q): xcd = f&7
// keeps all 32 q-blocks of a bh-group on ONE XCD; 3 bh-groups/XCD = 1.5 MB
// K/V working set, L2-resident (4 MB). gload_lds then fills from L2, not
// L3/HBM, shortening the per-tile vmcnt drain.
// ---------------------------------------------------------------------------
__global__ __launch_bounds__(256) void attn_kernel(
    const ush* __restrict__ Qb, const ush* __restrict__ Kb, const ush* __restrict__ Vtb,
    const float* __restrict__ pb, const int* __restrict__ mask, const float* __restrict__ coeff,
    ush* __restrict__ Att)
{
    __shared__ ush  Ks[2][64 * 64];    // ping-pong [key][d], chunk-swizzled
    __shared__ ush  Vs[2][64 * 64];    // ping-pong [d][key], chunk-swizzled
    __shared__ ush  Ps[64 * 72];       // P rows [q][key] (wave-private)
    __shared__ float kb_all[S_];       // per-key bias (pre-scaled by log2e)

    // XCD-locality remap: f in [0,768); xcd = f&7; j = f>>3 in [0,96);
    // bh = xcd*3 + (j>>5) in [0,24); q0 = (j&31)*64. Bijective.
    const int f    = blockIdx.x + 32 * (blockIdx.y + 12 * blockIdx.z);
    const int jj   = f >> 3;
    const int bh   = (f & 7) * 3 + (jj >> 5);
    const int q0   = (jj & 31) * 64;
    const int h    = bh % H_;
    const int b    = bh / H_;

    const int t  = threadIdx.x;
    const int wid = t >> 6;
    const int lane = t & 63;
    const int quad = lane >> 4;
    const int l16  = lane & 15;
    const int srow = lane >> 3;
    const int schk = lane & 7;

    const float ch = coeff[h];
    const float LOG2E = 1.44269504f;

    // per-key bias for the whole row: ((mask?0:-1e30) - ch*pb[k]) * log2e
    #pragma unroll
    for (int i = 0; i < 8; ++i) {
        const int idx = t + i * 256;
        const int gi = b * S_ + idx;
        kb_all[idx] = ((mask[gi] ? 0.f : -1e30f) - ch * pb[gi]) * LOG2E;
    }

    // register ones B-frag: output col 0 = 1.0, rest 0 (row-sum column)
    short8 b1v;
    {
        const short v1 = (l16 == 0) ? (short)0x3F80 : (short)0;
        b1v = (short8){v1, v1, v1, v1, v1, v1, v1, v1};
    }

    const int qrow = q0 + wid * 16 + l16;
    short8 aQ[2];
    #pragma unroll
    for (int ks = 0; ks < 2; ++ks)
        aQ[ks] = *(const short8*)&Qb[((size_t)bh * S_ + qrow) * D_ + quad * 8 + ks * 32];

    float hp[4];
    #pragma unroll
    for (int r = 0; r < 4; ++r)
        hp[r] = ch * pb[b * S_ + q0 + wid * 16 + quad * 4 + r] * LOG2E;

    f32x4 O[5];                        // O[4] = row-sum accumulator (ones frag)
    #pragma unroll
    for (int g = 0; g < 5; ++g) O[g] = (f32x4){0.f, 0.f, 0.f, 0.f};

    // prologue: stage tile 0 into buffer 0
    #pragma unroll
    for (int j = 0; j < 2; ++j) {
        const int r8 = wid * 16 + j * 8;
        const int r  = r8 + srow;
        const int c  = schk ^ (r & 7);
        GLOAD16(&Kb[((size_t)bh * S_ + r) * D_ + c * 8], &Ks[0][r8 * 64]);
        GLOAD16(&Vtb[((size_t)bh * D_ + r) * S_ + c * 8], &Vs[0][r8 * 64]);
    }
    __syncthreads();   // drains vmcnt; also orders kb_all init

    int p = 0;
    for (int kt = 0; kt < S_ / 64; ++kt) {
        // issue next tile's loads (latency hides under QK/softmax/PV)
        if (kt + 1 < S_ / 64) {
            const int kn = (kt + 1) * 64;
            #pragma unroll
            for (int j = 0; j < 2; ++j) {
                const int r8 = wid * 16 + j * 8;
                const int r  = r8 + srow;
                const int c  = schk ^ (r & 7);
                GLOAD16(&Kb[((size_t)bh * S_ + kn + r) * D_ + c * 8], &Ks[p ^ 1][r8 * 64]);
                GLOAD16(&Vtb[((size_t)bh * D_ + r) * S_ + kn + c * 8], &Vs[p ^ 1][r8 * 64]);
            }
        }

        // kbv early (lgkm overlap with QK MFMAs)
        float kbv[4];
        #pragma unroll
        for (int cg = 0; cg < 4; ++cg) kbv[cg] = kb_all[kt * 64 + cg * 16 + l16];

        // ---- QK^T ---- (T5: prioritize the MFMA cluster)
        f32x4 Sc[4];
        #pragma unroll
        for (int cg = 0; cg < 4; ++cg) Sc[cg] = (f32x4){0.f, 0.f, 0.f, 0.f};
        __builtin_amdgcn_s_setprio(1);
        #pragma unroll
        for (int ks = 0; ks < 2; ++ks) {
            #pragma unroll
            for (int cg = 0; cg < 4; ++cg) {
                const int rk = cg * 16 + l16;
                short8 bK = *(const short8*)&Ks[p][rk * 64 + ((quad + ks * 4) ^ (rk & 7)) * 8];
                Sc[cg] = __builtin_amdgcn_mfma_f32_16x16x32_bf16(aQ[ks], bK, Sc[cg], 0, 0, 0);
            }
        }
        __builtin_amdgcn_s_setprio(0);

        // ---- softmax + PV interleaved by ks-half ----
        // half=0: write Ps cols 0..31 (cg 0,1) then PV ks=0 (reads cols 0..31)
        // half=1: write Ps cols 32..63 (cg 2,3) then PV ks=1
        #pragma unroll
        for (int half = 0; half < 2; ++half) {
            #pragma unroll
            for (int cgi = 0; cgi < 2; ++cgi) {
                const int cg = half * 2 + cgi;
                #pragma unroll
                for (int r = 0; r < 4; ++r) {
                    float s = fmaf(Sc[cg][r], 0.18033688f, hp[r] + kbv[cg]);
                    float pe = __builtin_amdgcn_exp2f(s);  // masked: -> 0
                    Ps[(wid * 16 + quad * 4 + r) * 72 + cg * 16 + l16] =
                        (ush)(__float_as_uint(pe) >> 16);
                }
            }
            // PV for this half (aP reads only the cols written above;
            // same-wave lgkm ordering suffices — Ps rows are wave-private)
            short8 aP = *(const short8*)&Ps[(wid * 16 + l16) * 72 + quad * 8 + half * 32];
            __builtin_amdgcn_s_setprio(1);
            #pragma unroll
            for (int g = 0; g < 4; ++g) {
                const int rv = g * 16 + l16;
                short8 bV = *(const short8*)&Vs[p][rv * 64 + ((quad + half * 4) ^ (rv & 7)) * 8];
                O[g] = __builtin_amdgcn_mfma_f32_16x16x32_bf16(aP, bV, O[g], 0, 0, 0);
            }
            O[4] = __builtin_amdgcn_mfma_f32_16x16x32_bf16(aP, b1v, O[4], 0, 0, 0);
            __builtin_amdgcn_s_setprio(0);
        }

        __syncthreads();   // next tile ready; all waves done with buf[p]
        p ^= 1;
    }

    // epilogue: l lives in lanes with l16==0 (col 0 of ones output)
    #pragma unroll
    for (int r = 0; r < 4; ++r) {
        const float l  = __shfl(O[4][r], (lane & 48));   // lane quad*16 (l16=0)
        const float rl = 1.f / l;
        const size_t ob = ((size_t)b * S_ + q0 + wid * 16 + quad * 4 + r) * E_ + h * 64;
        #pragma unroll
        for (int g = 0; g < 4; ++g)
            Att[ob + g * 16 + l16] = f2b(O[g][r] * rl);
    }
}

// ---------------------------------------------------------------------------
// Kernel 3: output projection (UNCHANGED, frozen since R4).
// ---------------------------------------------------------------------------
__global__ __launch_bounds__(256, 4) void fc_mfma_kernel(
    const ush* __restrict__ Ain, const ush* __restrict__ W,
    const float* __restrict__ bias, float* __restrict__ Out)
{
    __shared__ ush As[64 * 64];    //  8 KB
    __shared__ ush Bs[128 * 64];   // 16 KB

    const int bid0 = blockIdx.x + 64 * blockIdx.y;   // grid (64, 6)
    const int bid  = (bid0 & 7) * 48 + (bid0 >> 3);
    const int bx   = bid & 63;
    const int by   = bid >> 6;

    const int m0 = bx * 64;
    const int n0 = by * 128;
    const int t  = threadIdx.x;
    const int wid  = t >> 6;
    const int lane = t & 63;
    const int quad = lane >> 4;
    const int l16  = lane & 15;
    const int wr  = (wid >> 1) * 32;
    const int wcn = (wid & 1) * 64;
    const int srow = lane >> 3;
    const int schk = lane & 7;

    f32x4 acc[2][4];
    #pragma unroll
    for (int i = 0; i < 2; ++i)
        #pragma unroll
        for (int j = 0; j < 4; ++j) acc[i][j] = (f32x4){0.f, 0.f, 0.f, 0.f};

    for (int kt = 0; kt < E_ / 64; ++kt) {
        const int kb = kt * 64;
        // stage: A 16 rows/wave (2 calls), B 32 rows/wave (4 calls)
        #pragma unroll
        for (int j = 0; j < 2; ++j) {
            const int r = wid * 16 + j * 8 + srow;
            const int c = schk ^ (r & 7);
            GLOAD16(&Ain[(size_t)(m0 + r) * E_ + kb + c * 8], &As[(wid * 16 + j * 8) * 64]);
        }
        #pragma unroll
        for (int j = 0; j < 4; ++j) {
            const int r = wid * 32 + j * 8 + srow;
            const int c = schk ^ (r & 7);
            GLOAD16(&W[(size_t)(n0 + r) * E_ + kb + c * 8], &Bs[(wid * 32 + j * 8) * 64]);
        }
        __syncthreads();

        #pragma unroll
        for (int ks = 0; ks < 2; ++ks) {
            short8 bfr[4];
            #pragma unroll
            for (int nj = 0; nj < 4; ++nj) {
                const int rn = wcn + nj * 16 + l16;
                bfr[nj] = *(const short8*)&Bs[rn * 64 + ((quad + ks * 4) ^ (rn & 7)) * 8];
            }
            #pragma unroll
            for (int mi = 0; mi < 2; ++mi) {
                const int rm = wr + mi * 16 + l16;
                short8 a = *(const short8*)&As[rm * 64 + ((quad + ks * 4) ^ (rm & 7)) * 8];
                #pragma unroll
                for (int nj = 0; nj < 4; ++nj)
                    acc[mi][nj] = __builtin_amdgcn_mfma_f32_16x16x32_bf16(a, bfr[nj], acc[mi][nj], 0, 0, 0);
            }
        }
        __syncthreads();
    }

    #pragma unroll
    for (int nj = 0; nj < 4; ++nj) {
        const int n = n0 + wcn + nj * 16 + l16;
        const float bw = bias[n];
        #pragma unroll
        for (int mi = 0; mi < 2; ++mi)
            #pragma unroll
            for (int r = 0; r < 4; ++r) {
                const int m = m0 + wr + mi * 16 + quad * 4 + r;
                Out[(size_t)m * E_ + n] = acc[mi][nj][r] + bw;
            }
    }
}

// ---------------------------------------------------------------------------
extern "C" void kernel_launch(void* const* d_in, const int* in_sizes, int n_in,
                              void* d_out, int out_size, void* d_ws, size_t ws_size,
                              hipStream_t stream)
{
    const float* q_in  = (const float*)d_in[0];
    const float* k_in  = (const float*)d_in[1];
    const float* v_in  = (const float*)d_in[2];
    const float* pb    = (const float*)d_in[3];
    const int*   mask  = (const int*)d_in[4];
    const float* wq    = (const float*)d_in[5];
    const float* bq    = (const float*)d_in[6];
    const float* wk    = (const float*)d_in[7];
    const float* bk    = (const float*)d_in[8];
    const float* wv    = (const float*)d_in[9];
    const float* bv    = (const float*)d_in[10];
    const float* fw    = (const float*)d_in[11];
    const float* fb    = (const float*)d_in[12];
    const float* coeff = (const float*)d_in[13];
    float* out = (float*)d_out;

    const size_t per = (size_t)B_ * H_ * S_ * D_;   // 3,145,728 elements
    const size_t wel = (size_t)E_ * E_;             //   589,824 elements

    // Workspace layout (~43 MB). Wqb/Wkb/Wvb are contiguous -> Wall[2304][768].
    // Xqb is dead after qkv -> Att aliases it.
    ush* Qb   = (ush*)d_ws;
    ush* Kb   = Qb  + per;
    ush* Vtb  = Kb  + per;
    ush* Xqb  = Vtb + per;
    ush* Xkb  = Xqb + per;
    ush* Xvb  = Xkb + per;
    ush* Wqb  = Xvb + per;                          // == Wall
    ush* Wkb  = Wqb + wel;
    ush* Wvb  = Wkb + wel;
    ush* Wfb  = Wvb + wel;
    float2* rope = (float2*)(Wfb + wel);            // [S][32], 512 KB (8B-aligned)
    ush* Attb = Xqb;                                // alias, live after qkv

    convert_kernel<<<dim3(6016), 256, 0, stream>>>(
        q_in, k_in, v_in, wq, wk, wv, fw,
        Xqb, Xkb, Xvb, Wqb, Wkb, Wvb, Wfb, rope);

    qkv_mfma_kernel<<<dim3(32, 18), 256, 0, stream>>>(
        Xqb, Xkb, Xvb, Wqb, bq, bk, bv, rope, Qb, Kb, Vtb);

    attn_kernel<<<dim3(S_ / 64, H_, B_), 256, 0, stream>>>(
        Qb, Kb, Vtb, pb, mask, coeff, Attb);

    fc_mfma_kernel<<<dim3(64, 6), 256, 0, stream>>>(Attb, Wfb, fb, out);
}